// Round 12
// baseline (353.557 us; speedup 1.0000x reference)
//
#include <hip/hip_runtime.h>

typedef unsigned short u16;
typedef unsigned int u32;
typedef short s16x8 __attribute__((ext_vector_type(8)));
typedef float f32x4 __attribute__((ext_vector_type(4)));
typedef float f32x2 __attribute__((ext_vector_type(2)));
typedef u32 u32x4 __attribute__((ext_vector_type(4)));

#define NNODES 55296
#define NEDGES 221184
#define ROWS   110592   // B * NNODES
#define NBLK_SCAN 216   // NNODES / 256

// packed fp32 fma: acc.lo += a.lo*b.lo ; acc.hi += a.hi*b.hi
#define PK_FMA(acc, a, b) \
    asm("v_pk_fma_f32 %0, %1, %2, %0" : "+v"(acc) : "v"(a), "v"(b))

__device__ __forceinline__ u16 f2bf(float f) {
    union { float f; unsigned u; } v; v.f = f;
    unsigned r = (v.u + 0x7fffu + ((v.u >> 16) & 1u)) >> 16;
    return (u16)r;
}
__device__ __forceinline__ float bf2f(u16 u) {
    return __uint_as_float(((unsigned)u) << 16);
}

// ---------------------------------------------------------------------------
// hist + weight-pack fused (R9 proven).
// [0,128) ew2 | [128,132) pw1 | [132,136) pw2 | [136,148) wih | [148,160) whh
// ---------------------------------------------------------------------------
__global__ __launch_bounds__(256) void hist_pack_kernel(
    const int* __restrict__ edst, int* __restrict__ cnt,
    const float* __restrict__ ew2, u16* __restrict__ ew2f,
    const float* __restrict__ pw1, u16* __restrict__ pw1h, u16* __restrict__ pw1l,
    const float* __restrict__ pw2, u16* __restrict__ pw2h, u16* __restrict__ pw2l,
    const float* __restrict__ wih, u16* __restrict__ wihh, u16* __restrict__ wihl,
    const float* __restrict__ whh, u16* __restrict__ whhh, u16* __restrict__ whhl)
{
    int i = blockIdx.x * 256 + threadIdx.x;
    atomicAdd(&cnt[edst[i]], 1);

    int b = blockIdx.x;
    if (b < 160) {
        const float* src; u16 *hi, *lo; int ncols, trans, base;
        if (b < 128)      { src = ew2; hi = ew2f; lo = nullptr; ncols = 1024; trans = 0; base = 0;   }
        else if (b < 132) { src = pw1; hi = pw1h; lo = pw1l;    ncols = 32;   trans = 0; base = 128; }
        else if (b < 136) { src = pw2; hi = pw2h; lo = pw2l;    ncols = 32;   trans = 0; base = 132; }
        else if (b < 148) { src = wih; hi = wihh; lo = wihl;    ncols = 96;   trans = 1; base = 136; }
        else              { src = whh; hi = whhh; lo = whhl;    ncols = 96;   trans = 1; base = 148; }
        int idx = (b - base) * 256 + threadIdx.x;
        int t = idx >> 9, rr = idx & 511, lane = rr >> 3, j = rr & 7;
        int k = (lane >> 4) * 8 + j;
        int n = t * 16 + (lane & 15);
        float v = trans ? src[n * 32 + k] : src[k * ncols + n];
        u16 hb = f2bf(v);
        hi[idx] = hb;
        if (lo) lo[idx] = f2bf(v - bf2f(hb));
    }
}

__global__ __launch_bounds__(256) void scan1_kernel(
    const int* __restrict__ cnt, int* __restrict__ exc, int* __restrict__ bsum)
{
    __shared__ int s[256];
    int t = threadIdx.x, g = blockIdx.x * 256 + t;
    int v = cnt[g];
    s[t] = v; __syncthreads();
#pragma unroll
    for (int d = 1; d < 256; d <<= 1) {
        int x = (t >= d) ? s[t - d] : 0;
        __syncthreads();
        s[t] += x;
        __syncthreads();
    }
    exc[g] = s[t] - v;
    if (t == 255) bsum[blockIdx.x] = s[255];
}

__global__ __launch_bounds__(256) void scan2_kernel(
    const int* __restrict__ bsum, int* __restrict__ bofs)
{
    __shared__ int s[256];
    int t = threadIdx.x;
    int v = (t < NBLK_SCAN) ? bsum[t] : 0;
    s[t] = v; __syncthreads();
#pragma unroll
    for (int d = 1; d < 256; d <<= 1) {
        int x = (t >= d) ? s[t - d] : 0;
        __syncthreads();
        s[t] += x;
        __syncthreads();
    }
    if (t < NBLK_SCAN) bofs[t] = s[t] - v;
}

// ---------------------------------------------------------------------------
// scatter + edge-MLP fused (R9 proven).
// ---------------------------------------------------------------------------
__global__ __launch_bounds__(256) void scatter_mlp_kernel(
    const int* __restrict__ edst, const int* __restrict__ esrc,
    const int* __restrict__ exc, const int* __restrict__ bofs,
    int* __restrict__ cnt,
    int* __restrict__ esrcp, int* __restrict__ edstp,
    const float* __restrict__ er, const float* __restrict__ ew1,
    const float* __restrict__ eb1, u16* __restrict__ rbf)
{
    __shared__ float w_lds[128];
    __shared__ float b_lds[32];
    int tid = threadIdx.x;
    if (tid < 128) w_lds[tid] = ew1[tid];
    else if (tid < 160) b_lds[tid - 128] = eb1[tid - 128];
    __syncthreads();

    int i = blockIdx.x * 256 + tid;
    int d = edst[i];
    int slot = atomicSub(&cnt[d], 1) - 1;
    int pos = exc[d] + bofs[d >> 8] + slot;
    esrcp[pos] = esrc[i];
    edstp[pos] = d;

    f32x4 e4 = *(const f32x4*)(er + (size_t)i * 4);
    u32 pk[16];
#pragma unroll
    for (int o2 = 0; o2 < 16; ++o2) {
        int o0 = o2 * 2, o1 = o2 * 2 + 1;
        float v0 = b_lds[o0] + e4.x * w_lds[o0] + e4.y * w_lds[32 + o0]
                             + e4.z * w_lds[64 + o0] + e4.w * w_lds[96 + o0];
        float v1 = b_lds[o1] + e4.x * w_lds[o1] + e4.y * w_lds[32 + o1]
                             + e4.z * w_lds[64 + o1] + e4.w * w_lds[96 + o1];
        u16 h0 = f2bf(fmaxf(v0, 0.f));
        u16 h1 = f2bf(fmaxf(v1, 0.f));
        pk[o2] = (u32)h0 | ((u32)h1 << 16);
    }
    u32* dst = (u32*)(rbf + (size_t)pos * 32);
#pragma unroll
    for (int q = 0; q < 4; ++q) {
        u32x4 v = {pk[q*4], pk[q*4+1], pk[q*4+2], pk[q*4+3]};
        *(u32x4*)(dst + q * 4) = v;
    }
}

// ---------------------------------------------------------------------------
// Node projection (R9 proven): st_f32 only + agg zero.
// ---------------------------------------------------------------------------
__global__ __launch_bounds__(256) void nodeproj_kernel(
    const float* __restrict__ x,
    const u16* __restrict__ pw1h, const u16* __restrict__ pw1l, const float* __restrict__ pb1,
    const u16* __restrict__ pw2h, const u16* __restrict__ pw2l, const float* __restrict__ pb2,
    float* __restrict__ st_f32, float* __restrict__ agg)
{
    __shared__ alignas(16) u16 t_hi[4][512];
    __shared__ alignas(16) u16 t_lo[4][512];
    int tid = threadIdx.x, wave = tid >> 6, lane = tid & 63;
    int quad = lane >> 4, col = lane & 15;
    int row0 = (blockIdx.x * 4 + wave) * 16;

    {
        f32x4 z = {0,0,0,0};
        float* zp = agg + (size_t)(row0 + col) * 32 + quad * 8;
        *(f32x4*)(zp) = z; *(f32x4*)(zp + 4) = z;
    }

    const float* xp = x + (size_t)(row0 + col) * 32 + quad * 8;
    f32x4 xv0 = *(const f32x4*)(xp), xv1 = *(const f32x4*)(xp + 4);
    s16x8 ah, al;
#pragma unroll
    for (int i = 0; i < 4; ++i) {
        u16 h0 = f2bf(xv0[i]); ah[i] = (short)h0; al[i] = (short)f2bf(xv0[i] - bf2f(h0));
        u16 h1 = f2bf(xv1[i]); ah[4+i] = (short)h1; al[4+i] = (short)f2bf(xv1[i] - bf2f(h1));
    }
#pragma unroll
    for (int t = 0; t < 2; ++t) {
        s16x8 bh = *(const s16x8*)(pw1h + t * 512 + lane * 8);
        s16x8 bl = *(const s16x8*)(pw1l + t * 512 + lane * 8);
        f32x4 acc = {0,0,0,0};
        acc = __builtin_amdgcn_mfma_f32_16x16x32_bf16(al, bh, acc, 0,0,0);
        acc = __builtin_amdgcn_mfma_f32_16x16x32_bf16(ah, bl, acc, 0,0,0);
        acc = __builtin_amdgcn_mfma_f32_16x16x32_bf16(ah, bh, acc, 0,0,0);
        float bias = pb1[t * 16 + col];
#pragma unroll
        for (int r = 0; r < 4; ++r) {
            float v = fmaxf(acc[r] + bias, 0.f);
            u16 hb = f2bf(v);
            int idx = (quad * 4 + r) * 32 + t * 16 + col;
            t_hi[wave][idx] = hb;
            t_lo[wave][idx] = f2bf(v - bf2f(hb));
        }
    }
    __syncthreads();
    s16x8 th = *(const s16x8*)(&t_hi[wave][col * 32 + quad * 8]);
    s16x8 tl = *(const s16x8*)(&t_lo[wave][col * 32 + quad * 8]);
#pragma unroll
    for (int t = 0; t < 2; ++t) {
        s16x8 bh = *(const s16x8*)(pw2h + t * 512 + lane * 8);
        s16x8 bl = *(const s16x8*)(pw2l + t * 512 + lane * 8);
        f32x4 acc = {0,0,0,0};
        acc = __builtin_amdgcn_mfma_f32_16x16x32_bf16(tl, bh, acc, 0,0,0);
        acc = __builtin_amdgcn_mfma_f32_16x16x32_bf16(th, bl, acc, 0,0,0);
        acc = __builtin_amdgcn_mfma_f32_16x16x32_bf16(th, bh, acc, 0,0,0);
        float bias = pb2[t * 16 + col];
#pragma unroll
        for (int r = 0; r < 4; ++r) {
            float v = acc[r] + bias;
            int row = row0 + quad * 4 + r;
            int o = t * 16 + col;
            st_f32[(size_t)row * 32 + o] = v;
        }
    }
}

// ---------------------------------------------------------------------------
// Message kernel v9: R9 structure (4 waves/block, 16 edges/wave, pk-FMA
// epilogue, eb2 in MFMA C, bank-padded transposed ns) but the ew2f fragment
// table is staged per-hh into LDS ONCE PER BLOCK (4 KB, one dwordx4/thread)
// instead of each wave pulling 64 KB from L2. Cuts ew2f L2 traffic 4x
// (884 -> 221 MB/step); two block barriers per hh. eb2 bias read direct
// from global (L2-hot; shown harmless in R11). LDS total 23.3 KB = R9's
// occupancy tier.
// ---------------------------------------------------------------------------
__global__ __launch_bounds__(256) void msg_kernel(
    const u16* __restrict__ rbf, const u16* __restrict__ ew2f,
    const float* __restrict__ eb2, const float* __restrict__ state,
    const int* __restrict__ esrcp, const int* __restrict__ edstp,
    float* __restrict__ agg)
{
    __shared__ alignas(16) u16 wfrag[2048];          // current hh: 4 fragments x 512 u16
    __shared__ alignas(16) float ns_lds[4][1200];    // [wave][ri*18 + (ri>>4)*16 + e]
    int tid = threadIdx.x;
    int wave = tid >> 6, lane = tid & 63;
    int quad = lane >> 4, col = lane & 15;
    int e0 = (blockIdx.x * 4 + wave) * 16;   // sorted edge positions

    // A fragment: 16 edges x K=32 (sorted-order rbf, coalesced)
    s16x8 afrag = *(const s16x8*)(rbf + (size_t)(e0 + col) * 32 + quad * 8);

    // stage gathered node features TRANSPOSED with bank pad (wave-local)
    {
        int el = lane >> 2, part = lane & 3;
        int b = part >> 1, hhalf = part & 1;
        int src = esrcp[e0 + el];
        const float* sp = state + (size_t)(b * NNODES + src) * 32 + hhalf * 16;
        f32x4 a0 = *(const f32x4*)(sp + 0);
        f32x4 a1 = *(const f32x4*)(sp + 4);
        f32x4 a2 = *(const f32x4*)(sp + 8);
        f32x4 a3 = *(const f32x4*)(sp + 12);
        float* wb = &ns_lds[wave][(b * 32 + hhalf * 16) * 18 + part * 16 + el];
        wb[0*18] = a0.x; wb[1*18] = a0.y; wb[2*18] = a0.z; wb[3*18] = a0.w;
        wb[4*18] = a1.x; wb[5*18] = a1.y; wb[6*18] = a1.z; wb[7*18] = a1.w;
        wb[8*18] = a2.x; wb[9*18] = a2.y; wb[10*18] = a2.z; wb[11*18] = a2.w;
        wb[12*18] = a3.x; wb[13*18] = a3.y; wb[14*18] = a3.z; wb[15*18] = a3.w;
    }
    int dstid[4];
#pragma unroll
    for (int r = 0; r < 4; ++r) dstid[r] = edstp[e0 + quad * 4 + r];

    f32x2 m[2][2][2];   // [b][o-half][r-pair]
#pragma unroll
    for (int b = 0; b < 2; ++b)
#pragma unroll
        for (int oh = 0; oh < 2; ++oh)
#pragma unroll
            for (int p = 0; p < 2; ++p) m[b][oh][p] = f32x2{0.f, 0.f};

    const float* nsw = &ns_lds[wave][0];
    int ep = quad * 4;

    for (int hh = 0; hh < 16; ++hh) {
        __syncthreads();   // prior iteration's wfrag reads complete (also orders ns at hh=0)
        // cooperative stage: 4 KB = 256 threads x 16 B
        *(((u32x4*)wfrag) + tid) =
            *(((const u32x4*)(ew2f + (size_t)hh * 2048)) + tid);
        __syncthreads();   // stage visible block-wide

        int h0 = hh * 2, h1 = hh * 2 + 1;
        int g = (hh >= 8) ? 1 : 0;
        s16x8 b0 = *(const s16x8*)(wfrag + 0 * 512 + lane * 8);
        s16x8 b1 = *(const s16x8*)(wfrag + 1 * 512 + lane * 8);
        s16x8 b2 = *(const s16x8*)(wfrag + 2 * 512 + lane * 8);
        s16x8 b3 = *(const s16x8*)(wfrag + 3 * 512 + lane * 8);
        // eb2 direct from global (L2/L1-hot, uniform per lane-col)
        float e00 = eb2[h0 * 32 + col],  e01 = eb2[h0 * 32 + 16 + col];
        float e10 = eb2[h1 * 32 + col],  e11 = eb2[h1 * 32 + 16 + col];
        f32x4 c0 = {e00, e00, e00, e00};
        f32x4 c1 = {e01, e01, e01, e01};
        f32x4 c2 = {e10, e10, e10, e10};
        f32x4 c3 = {e11, e11, e11, e11};
        f32x4 d0 = __builtin_amdgcn_mfma_f32_16x16x32_bf16(afrag, b0, c0, 0,0,0);
        f32x4 d1 = __builtin_amdgcn_mfma_f32_16x16x32_bf16(afrag, b1, c1, 0,0,0);
        f32x4 d2 = __builtin_amdgcn_mfma_f32_16x16x32_bf16(afrag, b2, c2, 0,0,0);
        f32x4 d3 = __builtin_amdgcn_mfma_f32_16x16x32_bf16(afrag, b3, c3, 0,0,0);
        f32x2 d0l = __builtin_shufflevector(d0, d0, 0, 1), d0h = __builtin_shufflevector(d0, d0, 2, 3);
        f32x2 d1l = __builtin_shufflevector(d1, d1, 0, 1), d1h = __builtin_shufflevector(d1, d1, 2, 3);
        f32x2 d2l = __builtin_shufflevector(d2, d2, 0, 1), d2h = __builtin_shufflevector(d2, d2, 2, 3);
        f32x2 d3l = __builtin_shufflevector(d3, d3, 0, 1), d3h = __builtin_shufflevector(d3, d3, 2, 3);
        const float* r00 = nsw + h0 * 18 + g * 16 + ep;
        const float* r01 = nsw + h1 * 18 + g * 16 + ep;
        const float* r10 = nsw + (32 + h0) * 18 + (2 + g) * 16 + ep;
        const float* r11 = nsw + (32 + h1) * 18 + (2 + g) * 16 + ep;
        f32x2 n00a = *(const f32x2*)(r00), n00b = *(const f32x2*)(r00 + 2);
        f32x2 n01a = *(const f32x2*)(r01), n01b = *(const f32x2*)(r01 + 2);
        f32x2 n10a = *(const f32x2*)(r10), n10b = *(const f32x2*)(r10 + 2);
        f32x2 n11a = *(const f32x2*)(r11), n11b = *(const f32x2*)(r11 + 2);
        PK_FMA(m[0][0][0], n00a, d0l); PK_FMA(m[0][0][0], n01a, d2l);
        PK_FMA(m[0][0][1], n00b, d0h); PK_FMA(m[0][0][1], n01b, d2h);
        PK_FMA(m[0][1][0], n00a, d1l); PK_FMA(m[0][1][0], n01a, d3l);
        PK_FMA(m[0][1][1], n00b, d1h); PK_FMA(m[0][1][1], n01b, d3h);
        PK_FMA(m[1][0][0], n10a, d0l); PK_FMA(m[1][0][0], n11a, d2l);
        PK_FMA(m[1][0][1], n10b, d0h); PK_FMA(m[1][0][1], n11b, d2h);
        PK_FMA(m[1][1][0], n10a, d1l); PK_FMA(m[1][1][0], n11a, d3l);
        PK_FMA(m[1][1][1], n10b, d1h); PK_FMA(m[1][1][1], n11b, d3h);
    }
    float msgs[2][2][4];
#pragma unroll
    for (int b = 0; b < 2; ++b)
#pragma unroll
        for (int oh = 0; oh < 2; ++oh) {
            msgs[b][oh][0] = m[b][oh][0].x; msgs[b][oh][1] = m[b][oh][0].y;
            msgs[b][oh][2] = m[b][oh][1].x; msgs[b][oh][3] = m[b][oh][1].y;
        }
    bool valid[4] = {true, true, true, true};
#pragma unroll
    for (int r = 3; r >= 1; --r) {
        if (dstid[r] == dstid[r - 1]) {
            valid[r] = false;
            msgs[0][0][r-1] += msgs[0][0][r];
            msgs[0][1][r-1] += msgs[0][1][r];
            msgs[1][0][r-1] += msgs[1][0][r];
            msgs[1][1][r-1] += msgs[1][1][r];
        }
    }
#pragma unroll
    for (int r = 0; r < 4; ++r) {
        if (valid[r]) {
#pragma unroll
            for (int b = 0; b < 2; ++b) {
                float* base = agg + ((size_t)b * NNODES + dstid[r]) * 32;
                unsafeAtomicAdd(base + col,      msgs[b][0][r]);
                unsafeAtomicAdd(base + 16 + col, msgs[b][1][r]);
            }
        }
    }
}

// ---------------------------------------------------------------------------
// GRU step (R7/R9 proven). UNCHANGED.
// ---------------------------------------------------------------------------
__global__ __launch_bounds__(256) void gru_kernel(
    float* __restrict__ agg, const float* __restrict__ conv_b,
    const float* __restrict__ st_f32,
    const u16* __restrict__ wihh, const u16* __restrict__ wihl,
    const u16* __restrict__ whhh, const u16* __restrict__ whhl,
    const float* __restrict__ b_ih, const float* __restrict__ b_hh,
    float* __restrict__ out_f32, int zero_agg)
{
    int tid = threadIdx.x, wave = tid >> 6, lane = tid & 63;
    int quad = lane >> 4, col = lane & 15;
    int row0 = (blockIdx.x * 4 + wave) * 16;

    float* ap = agg + (size_t)(row0 + col) * 32 + quad * 8;
    f32x4 av0 = *(const f32x4*)(ap), av1 = *(const f32x4*)(ap + 4);
    if (zero_agg) {
        f32x4 z = {0,0,0,0};
        *(f32x4*)(ap) = z; *(f32x4*)(ap + 4) = z;
    }
    const float* cb = conv_b + quad * 8;
    f32x4 cb0 = *(const f32x4*)(cb), cb1 = *(const f32x4*)(cb + 4);
    s16x8 anh, anl;
#pragma unroll
    for (int i = 0; i < 4; ++i) {
        float v0 = fmaxf(av0[i] + cb0[i], 0.f);
        float v1 = fmaxf(av1[i] + cb1[i], 0.f);
        u16 h0 = f2bf(v0); anh[i] = (short)h0;   anl[i] = (short)f2bf(v0 - bf2f(h0));
        u16 h1 = f2bf(v1); anh[4+i] = (short)h1; anl[4+i] = (short)f2bf(v1 - bf2f(h1));
    }
    const float* hp = st_f32 + (size_t)(row0 + col) * 32 + quad * 8;
    f32x4 hv0 = *(const f32x4*)(hp), hv1 = *(const f32x4*)(hp + 4);
    s16x8 ahh, ahl;
#pragma unroll
    for (int i = 0; i < 4; ++i) {
        u16 h0 = f2bf(hv0[i]); ahh[i] = (short)h0;   ahl[i] = (short)f2bf(hv0[i] - bf2f(h0));
        u16 h1 = f2bf(hv1[i]); ahh[4+i] = (short)h1; ahl[4+i] = (short)f2bf(hv1[i] - bf2f(h1));
    }

    f32x4 gx[6], gh[6];
#pragma unroll
    for (int t = 0; t < 6; ++t) {
        s16x8 bh = *(const s16x8*)(wihh + t * 512 + lane * 8);
        s16x8 bl = *(const s16x8*)(wihl + t * 512 + lane * 8);
        f32x4 acc = {0,0,0,0};
        acc = __builtin_amdgcn_mfma_f32_16x16x32_bf16(anl, bh, acc, 0,0,0);
        acc = __builtin_amdgcn_mfma_f32_16x16x32_bf16(anh, bl, acc, 0,0,0);
        acc = __builtin_amdgcn_mfma_f32_16x16x32_bf16(anh, bh, acc, 0,0,0);
        gx[t] = acc;
        s16x8 ch = *(const s16x8*)(whhh + t * 512 + lane * 8);
        s16x8 cl = *(const s16x8*)(whhl + t * 512 + lane * 8);
        f32x4 acc2 = {0,0,0,0};
        acc2 = __builtin_amdgcn_mfma_f32_16x16x32_bf16(ahl, ch, acc2, 0,0,0);
        acc2 = __builtin_amdgcn_mfma_f32_16x16x32_bf16(ahh, cl, acc2, 0,0,0);
        acc2 = __builtin_amdgcn_mfma_f32_16x16x32_bf16(ahh, ch, acc2, 0,0,0);
        gh[t] = acc2;
    }
    float bihv[6], bhhv[6];
#pragma unroll
    for (int t = 0; t < 6; ++t) { bihv[t] = b_ih[t * 16 + col]; bhhv[t] = b_hh[t * 16 + col]; }

#pragma unroll
    for (int r = 0; r < 4; ++r) {
        int row = row0 + quad * 4 + r;
#pragma unroll
        for (int oh = 0; oh < 2; ++oh) {
            int o = oh * 16 + col;
            float hid = st_f32[(size_t)row * 32 + o];
            float sr = (gx[oh][r] + bihv[oh]) + (gh[oh][r] + bhhv[oh]);
            float sz = (gx[2+oh][r] + bihv[2+oh]) + (gh[2+oh][r] + bhhv[2+oh]);
            float gxn = gx[4+oh][r] + bihv[4+oh];
            float ghn = gh[4+oh][r] + bhhv[4+oh];
            float rr = 1.f / (1.f + __expf(-sr));
            float zz = 1.f / (1.f + __expf(-sz));
            float narg = gxn + rr * ghn;
            float ex = __expf(2.f * narg);
            float nn = (ex - 1.f) / (ex + 1.f);
            float hnew = (1.f - zz) * nn + zz * hid;
            out_f32[(size_t)row * 32 + o] = hnew;
        }
    }
}

// ---------------------------------------------------------------------------
extern "C" void kernel_launch(void* const* d_in, const int* in_sizes, int n_in,
                              void* d_out, int out_size, void* d_ws, size_t ws_size,
                              hipStream_t stream)
{
    const float* x      = (const float*)d_in[0];
    const float* er     = (const float*)d_in[1];
    const float* pw1    = (const float*)d_in[2];
    const float* pb1    = (const float*)d_in[3];
    const float* pw2    = (const float*)d_in[4];
    const float* pb2    = (const float*)d_in[5];
    const float* ew1    = (const float*)d_in[6];
    const float* eb1    = (const float*)d_in[7];
    const float* ew2    = (const float*)d_in[8];
    const float* eb2    = (const float*)d_in[9];
    const float* conv_b = (const float*)d_in[10];
    const float* wih    = (const float*)d_in[11];
    const float* whh    = (const float*)d_in[12];
    const float* bih    = (const float*)d_in[13];
    const float* bhh    = (const float*)d_in[14];
    const int*   esrc   = (const int*)d_in[15];
    const int*   edst   = (const int*)d_in[16];
    float* out = (float*)d_out;

    char* ws = (char*)d_ws;
    size_t off = 0;
    auto alloc = [&](size_t bytes) -> void* {
        void* p = ws + off;
        off = (off + bytes + 255) & ~(size_t)255;
        return p;
    };
    u16*   rbf    = (u16*)  alloc((size_t)(NEDGES + 32) * 32 * 2);
    float* st_f32 = (float*)alloc((size_t)ROWS * 32 * 4);
    float* agg    = (float*)alloc((size_t)ROWS * 32 * 4);
    u16*   ew2f   = (u16*)  alloc(64 * 512 * 2);
    u16*   pw1h   = (u16*)  alloc(2 * 512 * 2);
    u16*   pw1l   = (u16*)  alloc(2 * 512 * 2);
    u16*   pw2h   = (u16*)  alloc(2 * 512 * 2);
    u16*   pw2l   = (u16*)  alloc(2 * 512 * 2);
    u16*   wihhf  = (u16*)  alloc(6 * 512 * 2);
    u16*   wihlf  = (u16*)  alloc(6 * 512 * 2);
    u16*   whhhf  = (u16*)  alloc(6 * 512 * 2);
    u16*   whhlf  = (u16*)  alloc(6 * 512 * 2);
    // sort infrastructure
    int*   cnt      = (int*)alloc((size_t)NNODES * 4);
    int*   exc      = (int*)alloc((size_t)NNODES * 4);
    int*   bsum     = (int*)alloc(NBLK_SCAN * 4);
    int*   bofs     = (int*)alloc(NBLK_SCAN * 4);
    int*   esrcp    = (int*)alloc((size_t)(NEDGES + 32) * 4);
    int*   edstp    = (int*)alloc((size_t)(NEDGES + 32) * 4);
    (void)in_sizes; (void)n_in; (void)out_size; (void)ws_size;

    // --- one-time: sort edges by dst (hist fused with weight pack) ---
    hipMemsetAsync(cnt, 0, (size_t)NNODES * 4, stream);
    hist_pack_kernel<<<NEDGES / 256, 256, 0, stream>>>(
        edst, cnt, ew2, ew2f, pw1, pw1h, pw1l, pw2, pw2h, pw2l,
        wih, wihhf, wihlf, whh, whhhf, whhlf);
    scan1_kernel<<<NBLK_SCAN, 256, 0, stream>>>(cnt, exc, bsum);
    scan2_kernel<<<1, 256, 0, stream>>>(bsum, bofs);
    scatter_mlp_kernel<<<NEDGES / 256, 256, 0, stream>>>(
        edst, esrc, exc, bofs, cnt, esrcp, edstp, er, ew1, eb1, rbf);

    nodeproj_kernel<<<ROWS / 64, 256, 0, stream>>>(x, pw1h, pw1l, pb1, pw2h, pw2l, pb2,
                                                   st_f32, agg);
    for (int s = 0; s < 3; ++s) {
        msg_kernel<<<NEDGES / 64, 256, 0, stream>>>(rbf, ew2f, eb2, st_f32,
                                                    esrcp, edstp, agg);
        float* of = (s == 2) ? out : st_f32;
        gru_kernel<<<ROWS / 64, 256, 0, stream>>>(agg, conv_b, st_f32,
                                                  wihhf, wihlf, whhhf, whhlf, bih, bhh,
                                                  of, (s < 2) ? 1 : 0);
    }
}

// Round 13
// 336.533 us; speedup vs baseline: 1.0506x; 1.0506x over previous
//
#include <hip/hip_runtime.h>

typedef unsigned short u16;
typedef unsigned int u32;
typedef short s16x8 __attribute__((ext_vector_type(8)));
typedef float f32x4 __attribute__((ext_vector_type(4)));
typedef float f32x2 __attribute__((ext_vector_type(2)));
typedef u32 u32x4 __attribute__((ext_vector_type(4)));

#define NNODES 55296
#define NEDGES 221184
#define ROWS   110592   // B * NNODES
#define NBLK_SCAN 216   // NNODES / 256

// packed fp32 fma: acc.lo += a.lo*b.lo ; acc.hi += a.hi*b.hi
#define PK_FMA(acc, a, b) \
    asm("v_pk_fma_f32 %0, %1, %2, %0" : "+v"(acc) : "v"(a), "v"(b))

__device__ __forceinline__ u16 f2bf(float f) {
    union { float f; unsigned u; } v; v.f = f;
    unsigned r = (v.u + 0x7fffu + ((v.u >> 16) & 1u)) >> 16;
    return (u16)r;
}
__device__ __forceinline__ float bf2f(u16 u) {
    return __uint_as_float(((unsigned)u) << 16);
}

// ---------------------------------------------------------------------------
// hist + weight-pack fused (R9 proven).
// [0,128) ew2 | [128,132) pw1 | [132,136) pw2 | [136,148) wih | [148,160) whh
// ---------------------------------------------------------------------------
__global__ __launch_bounds__(256) void hist_pack_kernel(
    const int* __restrict__ edst, int* __restrict__ cnt,
    const float* __restrict__ ew2, u16* __restrict__ ew2f,
    const float* __restrict__ pw1, u16* __restrict__ pw1h, u16* __restrict__ pw1l,
    const float* __restrict__ pw2, u16* __restrict__ pw2h, u16* __restrict__ pw2l,
    const float* __restrict__ wih, u16* __restrict__ wihh, u16* __restrict__ wihl,
    const float* __restrict__ whh, u16* __restrict__ whhh, u16* __restrict__ whhl)
{
    int i = blockIdx.x * 256 + threadIdx.x;
    atomicAdd(&cnt[edst[i]], 1);

    int b = blockIdx.x;
    if (b < 160) {
        const float* src; u16 *hi, *lo; int ncols, trans, base;
        if (b < 128)      { src = ew2; hi = ew2f; lo = nullptr; ncols = 1024; trans = 0; base = 0;   }
        else if (b < 132) { src = pw1; hi = pw1h; lo = pw1l;    ncols = 32;   trans = 0; base = 128; }
        else if (b < 136) { src = pw2; hi = pw2h; lo = pw2l;    ncols = 32;   trans = 0; base = 132; }
        else if (b < 148) { src = wih; hi = wihh; lo = wihl;    ncols = 96;   trans = 1; base = 136; }
        else              { src = whh; hi = whhh; lo = whhl;    ncols = 96;   trans = 1; base = 148; }
        int idx = (b - base) * 256 + threadIdx.x;
        int t = idx >> 9, rr = idx & 511, lane = rr >> 3, j = rr & 7;
        int k = (lane >> 4) * 8 + j;
        int n = t * 16 + (lane & 15);
        float v = trans ? src[n * 32 + k] : src[k * ncols + n];
        u16 hb = f2bf(v);
        hi[idx] = hb;
        if (lo) lo[idx] = f2bf(v - bf2f(hb));
    }
}

__global__ __launch_bounds__(256) void scan1_kernel(
    const int* __restrict__ cnt, int* __restrict__ exc, int* __restrict__ bsum)
{
    __shared__ int s[256];
    int t = threadIdx.x, g = blockIdx.x * 256 + t;
    int v = cnt[g];
    s[t] = v; __syncthreads();
#pragma unroll
    for (int d = 1; d < 256; d <<= 1) {
        int x = (t >= d) ? s[t - d] : 0;
        __syncthreads();
        s[t] += x;
        __syncthreads();
    }
    exc[g] = s[t] - v;
    if (t == 255) bsum[blockIdx.x] = s[255];
}

__global__ __launch_bounds__(256) void scan2_kernel(
    const int* __restrict__ bsum, int* __restrict__ bofs)
{
    __shared__ int s[256];
    int t = threadIdx.x;
    int v = (t < NBLK_SCAN) ? bsum[t] : 0;
    s[t] = v; __syncthreads();
#pragma unroll
    for (int d = 1; d < 256; d <<= 1) {
        int x = (t >= d) ? s[t - d] : 0;
        __syncthreads();
        s[t] += x;
        __syncthreads();
    }
    if (t < NBLK_SCAN) bofs[t] = s[t] - v;
}

// ---------------------------------------------------------------------------
// scatter + edge-MLP fused (R9 proven).
// ---------------------------------------------------------------------------
__global__ __launch_bounds__(256) void scatter_mlp_kernel(
    const int* __restrict__ edst, const int* __restrict__ esrc,
    const int* __restrict__ exc, const int* __restrict__ bofs,
    int* __restrict__ cnt,
    int* __restrict__ esrcp, int* __restrict__ edstp,
    const float* __restrict__ er, const float* __restrict__ ew1,
    const float* __restrict__ eb1, u16* __restrict__ rbf)
{
    __shared__ float w_lds[128];
    __shared__ float b_lds[32];
    int tid = threadIdx.x;
    if (tid < 128) w_lds[tid] = ew1[tid];
    else if (tid < 160) b_lds[tid - 128] = eb1[tid - 128];
    __syncthreads();

    int i = blockIdx.x * 256 + tid;
    int d = edst[i];
    int slot = atomicSub(&cnt[d], 1) - 1;
    int pos = exc[d] + bofs[d >> 8] + slot;
    esrcp[pos] = esrc[i];
    edstp[pos] = d;

    f32x4 e4 = *(const f32x4*)(er + (size_t)i * 4);
    u32 pk[16];
#pragma unroll
    for (int o2 = 0; o2 < 16; ++o2) {
        int o0 = o2 * 2, o1 = o2 * 2 + 1;
        float v0 = b_lds[o0] + e4.x * w_lds[o0] + e4.y * w_lds[32 + o0]
                             + e4.z * w_lds[64 + o0] + e4.w * w_lds[96 + o0];
        float v1 = b_lds[o1] + e4.x * w_lds[o1] + e4.y * w_lds[32 + o1]
                             + e4.z * w_lds[64 + o1] + e4.w * w_lds[96 + o1];
        u16 h0 = f2bf(fmaxf(v0, 0.f));
        u16 h1 = f2bf(fmaxf(v1, 0.f));
        pk[o2] = (u32)h0 | ((u32)h1 << 16);
    }
    u32* dst = (u32*)(rbf + (size_t)pos * 32);
#pragma unroll
    for (int q = 0; q < 4; ++q) {
        u32x4 v = {pk[q*4], pk[q*4+1], pk[q*4+2], pk[q*4+3]};
        *(u32x4*)(dst + q * 4) = v;
    }
}

// ---------------------------------------------------------------------------
// Node projection (R9 proven): st_f32 only + agg zero.
// ---------------------------------------------------------------------------
__global__ __launch_bounds__(256) void nodeproj_kernel(
    const float* __restrict__ x,
    const u16* __restrict__ pw1h, const u16* __restrict__ pw1l, const float* __restrict__ pb1,
    const u16* __restrict__ pw2h, const u16* __restrict__ pw2l, const float* __restrict__ pb2,
    float* __restrict__ st_f32, float* __restrict__ agg)
{
    __shared__ alignas(16) u16 t_hi[4][512];
    __shared__ alignas(16) u16 t_lo[4][512];
    int tid = threadIdx.x, wave = tid >> 6, lane = tid & 63;
    int quad = lane >> 4, col = lane & 15;
    int row0 = (blockIdx.x * 4 + wave) * 16;

    {
        f32x4 z = {0,0,0,0};
        float* zp = agg + (size_t)(row0 + col) * 32 + quad * 8;
        *(f32x4*)(zp) = z; *(f32x4*)(zp + 4) = z;
    }

    const float* xp = x + (size_t)(row0 + col) * 32 + quad * 8;
    f32x4 xv0 = *(const f32x4*)(xp), xv1 = *(const f32x4*)(xp + 4);
    s16x8 ah, al;
#pragma unroll
    for (int i = 0; i < 4; ++i) {
        u16 h0 = f2bf(xv0[i]); ah[i] = (short)h0; al[i] = (short)f2bf(xv0[i] - bf2f(h0));
        u16 h1 = f2bf(xv1[i]); ah[4+i] = (short)h1; al[4+i] = (short)f2bf(xv1[i] - bf2f(h1));
    }
#pragma unroll
    for (int t = 0; t < 2; ++t) {
        s16x8 bh = *(const s16x8*)(pw1h + t * 512 + lane * 8);
        s16x8 bl = *(const s16x8*)(pw1l + t * 512 + lane * 8);
        f32x4 acc = {0,0,0,0};
        acc = __builtin_amdgcn_mfma_f32_16x16x32_bf16(al, bh, acc, 0,0,0);
        acc = __builtin_amdgcn_mfma_f32_16x16x32_bf16(ah, bl, acc, 0,0,0);
        acc = __builtin_amdgcn_mfma_f32_16x16x32_bf16(ah, bh, acc, 0,0,0);
        float bias = pb1[t * 16 + col];
#pragma unroll
        for (int r = 0; r < 4; ++r) {
            float v = fmaxf(acc[r] + bias, 0.f);
            u16 hb = f2bf(v);
            int idx = (quad * 4 + r) * 32 + t * 16 + col;
            t_hi[wave][idx] = hb;
            t_lo[wave][idx] = f2bf(v - bf2f(hb));
        }
    }
    __syncthreads();
    s16x8 th = *(const s16x8*)(&t_hi[wave][col * 32 + quad * 8]);
    s16x8 tl = *(const s16x8*)(&t_lo[wave][col * 32 + quad * 8]);
#pragma unroll
    for (int t = 0; t < 2; ++t) {
        s16x8 bh = *(const s16x8*)(pw2h + t * 512 + lane * 8);
        s16x8 bl = *(const s16x8*)(pw2l + t * 512 + lane * 8);
        f32x4 acc = {0,0,0,0};
        acc = __builtin_amdgcn_mfma_f32_16x16x32_bf16(tl, bh, acc, 0,0,0);
        acc = __builtin_amdgcn_mfma_f32_16x16x32_bf16(th, bl, acc, 0,0,0);
        acc = __builtin_amdgcn_mfma_f32_16x16x32_bf16(th, bh, acc, 0,0,0);
        float bias = pb2[t * 16 + col];
#pragma unroll
        for (int r = 0; r < 4; ++r) {
            float v = acc[r] + bias;
            int row = row0 + quad * 4 + r;
            int o = t * 16 + col;
            st_f32[(size_t)row * 32 + o] = v;
        }
    }
}

// ---------------------------------------------------------------------------
// Message + scatter kernel (R9 proven best: 4 waves/block, 16 edges/wave,
// pk-FMA epilogue over edge-pairs, eb2 bias via MFMA C operand from LDS-staged
// eb2, bank-padded transposed ns, dst-sorted atomics + quad-local dst merge).
// ---------------------------------------------------------------------------
__global__ __launch_bounds__(256) void msg_kernel(
    const u16* __restrict__ rbf, const u16* __restrict__ ew2f,
    const float* __restrict__ eb2, const float* __restrict__ state,
    const int* __restrict__ esrcp, const int* __restrict__ edstp,
    float* __restrict__ agg)
{
    __shared__ alignas(16) float eb2_lds[1024];
    __shared__ alignas(16) float ns_lds[4][1200];   // [wave][ri*18 + (ri>>4)*16 + e]
    int tid = threadIdx.x;
    {   // stage eb2 (block-wide)
        *(f32x4*)(eb2_lds + tid * 4) = *(const f32x4*)(eb2 + tid * 4);
    }
    int wave = tid >> 6, lane = tid & 63;
    int quad = lane >> 4, col = lane & 15;
    int e0 = (blockIdx.x * 4 + wave) * 16;   // sorted edge positions

    // A fragment: 16 edges x K=32 (sorted-order rbf, coalesced)
    s16x8 afrag = *(const s16x8*)(rbf + (size_t)(e0 + col) * 32 + quad * 8);

    // stage gathered node features TRANSPOSED with bank pad
    {
        int el = lane >> 2, part = lane & 3;
        int b = part >> 1, hhalf = part & 1;
        int src = esrcp[e0 + el];
        const float* sp = state + (size_t)(b * NNODES + src) * 32 + hhalf * 16;
        f32x4 a0 = *(const f32x4*)(sp + 0);
        f32x4 a1 = *(const f32x4*)(sp + 4);
        f32x4 a2 = *(const f32x4*)(sp + 8);
        f32x4 a3 = *(const f32x4*)(sp + 12);
        float* wb = &ns_lds[wave][(b * 32 + hhalf * 16) * 18 + part * 16 + el];
        wb[0*18] = a0.x; wb[1*18] = a0.y; wb[2*18] = a0.z; wb[3*18] = a0.w;
        wb[4*18] = a1.x; wb[5*18] = a1.y; wb[6*18] = a1.z; wb[7*18] = a1.w;
        wb[8*18] = a2.x; wb[9*18] = a2.y; wb[10*18] = a2.z; wb[11*18] = a2.w;
        wb[12*18] = a3.x; wb[13*18] = a3.y; wb[14*18] = a3.z; wb[15*18] = a3.w;
    }
    int dstid[4];
#pragma unroll
    for (int r = 0; r < 4; ++r) dstid[r] = edstp[e0 + quad * 4 + r];
    __syncthreads();

    f32x2 m[2][2][2];   // [b][o-half][r-pair]
#pragma unroll
    for (int b = 0; b < 2; ++b)
#pragma unroll
        for (int oh = 0; oh < 2; ++oh)
#pragma unroll
            for (int p = 0; p < 2; ++p) m[b][oh][p] = f32x2{0.f, 0.f};

    const float* nsw = &ns_lds[wave][0];
    int ep = quad * 4;
#pragma unroll 4
    for (int hh = 0; hh < 16; ++hh) {
        int h0 = hh * 2, h1 = hh * 2 + 1;
        int g = (hh >= 8) ? 1 : 0;
        s16x8 b0 = *(const s16x8*)(ew2f + (4 * hh + 0) * 512 + lane * 8);
        s16x8 b1 = *(const s16x8*)(ew2f + (4 * hh + 1) * 512 + lane * 8);
        s16x8 b2 = *(const s16x8*)(ew2f + (4 * hh + 2) * 512 + lane * 8);
        s16x8 b3 = *(const s16x8*)(ew2f + (4 * hh + 3) * 512 + lane * 8);
        float e00 = eb2_lds[h0 * 32 + col],  e01 = eb2_lds[h0 * 32 + 16 + col];
        float e10 = eb2_lds[h1 * 32 + col],  e11 = eb2_lds[h1 * 32 + 16 + col];
        f32x4 c0 = {e00, e00, e00, e00};
        f32x4 c1 = {e01, e01, e01, e01};
        f32x4 c2 = {e10, e10, e10, e10};
        f32x4 c3 = {e11, e11, e11, e11};
        f32x4 d0 = __builtin_amdgcn_mfma_f32_16x16x32_bf16(afrag, b0, c0, 0,0,0);
        f32x4 d1 = __builtin_amdgcn_mfma_f32_16x16x32_bf16(afrag, b1, c1, 0,0,0);
        f32x4 d2 = __builtin_amdgcn_mfma_f32_16x16x32_bf16(afrag, b2, c2, 0,0,0);
        f32x4 d3 = __builtin_amdgcn_mfma_f32_16x16x32_bf16(afrag, b3, c3, 0,0,0);
        f32x2 d0l = __builtin_shufflevector(d0, d0, 0, 1), d0h = __builtin_shufflevector(d0, d0, 2, 3);
        f32x2 d1l = __builtin_shufflevector(d1, d1, 0, 1), d1h = __builtin_shufflevector(d1, d1, 2, 3);
        f32x2 d2l = __builtin_shufflevector(d2, d2, 0, 1), d2h = __builtin_shufflevector(d2, d2, 2, 3);
        f32x2 d3l = __builtin_shufflevector(d3, d3, 0, 1), d3h = __builtin_shufflevector(d3, d3, 2, 3);
        const float* r00 = nsw + h0 * 18 + g * 16 + ep;
        const float* r01 = nsw + h1 * 18 + g * 16 + ep;
        const float* r10 = nsw + (32 + h0) * 18 + (2 + g) * 16 + ep;
        const float* r11 = nsw + (32 + h1) * 18 + (2 + g) * 16 + ep;
        f32x2 n00a = *(const f32x2*)(r00), n00b = *(const f32x2*)(r00 + 2);
        f32x2 n01a = *(const f32x2*)(r01), n01b = *(const f32x2*)(r01 + 2);
        f32x2 n10a = *(const f32x2*)(r10), n10b = *(const f32x2*)(r10 + 2);
        f32x2 n11a = *(const f32x2*)(r11), n11b = *(const f32x2*)(r11 + 2);
        PK_FMA(m[0][0][0], n00a, d0l); PK_FMA(m[0][0][0], n01a, d2l);
        PK_FMA(m[0][0][1], n00b, d0h); PK_FMA(m[0][0][1], n01b, d2h);
        PK_FMA(m[0][1][0], n00a, d1l); PK_FMA(m[0][1][0], n01a, d3l);
        PK_FMA(m[0][1][1], n00b, d1h); PK_FMA(m[0][1][1], n01b, d3h);
        PK_FMA(m[1][0][0], n10a, d0l); PK_FMA(m[1][0][0], n11a, d2l);
        PK_FMA(m[1][0][1], n10b, d0h); PK_FMA(m[1][0][1], n11b, d2h);
        PK_FMA(m[1][1][0], n10a, d1l); PK_FMA(m[1][1][0], n11a, d3l);
        PK_FMA(m[1][1][1], n10b, d1h); PK_FMA(m[1][1][1], n11b, d3h);
    }
    float msgs[2][2][4];
#pragma unroll
    for (int b = 0; b < 2; ++b)
#pragma unroll
        for (int oh = 0; oh < 2; ++oh) {
            msgs[b][oh][0] = m[b][oh][0].x; msgs[b][oh][1] = m[b][oh][0].y;
            msgs[b][oh][2] = m[b][oh][1].x; msgs[b][oh][3] = m[b][oh][1].y;
        }
    bool valid[4] = {true, true, true, true};
#pragma unroll
    for (int r = 3; r >= 1; --r) {
        if (dstid[r] == dstid[r - 1]) {
            valid[r] = false;
            msgs[0][0][r-1] += msgs[0][0][r];
            msgs[0][1][r-1] += msgs[0][1][r];
            msgs[1][0][r-1] += msgs[1][0][r];
            msgs[1][1][r-1] += msgs[1][1][r];
        }
    }
#pragma unroll
    for (int r = 0; r < 4; ++r) {
        if (valid[r]) {
#pragma unroll
            for (int b = 0; b < 2; ++b) {
                float* base = agg + ((size_t)b * NNODES + dstid[r]) * 32;
                unsafeAtomicAdd(base + col,      msgs[b][0][r]);
                unsafeAtomicAdd(base + 16 + col, msgs[b][1][r]);
            }
        }
    }
}

// ---------------------------------------------------------------------------
// GRU step (R7/R9 proven). UNCHANGED.
// ---------------------------------------------------------------------------
__global__ __launch_bounds__(256) void gru_kernel(
    float* __restrict__ agg, const float* __restrict__ conv_b,
    const float* __restrict__ st_f32,
    const u16* __restrict__ wihh, const u16* __restrict__ wihl,
    const u16* __restrict__ whhh, const u16* __restrict__ whhl,
    const float* __restrict__ b_ih, const float* __restrict__ b_hh,
    float* __restrict__ out_f32, int zero_agg)
{
    int tid = threadIdx.x, wave = tid >> 6, lane = tid & 63;
    int quad = lane >> 4, col = lane & 15;
    int row0 = (blockIdx.x * 4 + wave) * 16;

    float* ap = agg + (size_t)(row0 + col) * 32 + quad * 8;
    f32x4 av0 = *(const f32x4*)(ap), av1 = *(const f32x4*)(ap + 4);
    if (zero_agg) {
        f32x4 z = {0,0,0,0};
        *(f32x4*)(ap) = z; *(f32x4*)(ap + 4) = z;
    }
    const float* cb = conv_b + quad * 8;
    f32x4 cb0 = *(const f32x4*)(cb), cb1 = *(const f32x4*)(cb + 4);
    s16x8 anh, anl;
#pragma unroll
    for (int i = 0; i < 4; ++i) {
        float v0 = fmaxf(av0[i] + cb0[i], 0.f);
        float v1 = fmaxf(av1[i] + cb1[i], 0.f);
        u16 h0 = f2bf(v0); anh[i] = (short)h0;   anl[i] = (short)f2bf(v0 - bf2f(h0));
        u16 h1 = f2bf(v1); anh[4+i] = (short)h1; anl[4+i] = (short)f2bf(v1 - bf2f(h1));
    }
    const float* hp = st_f32 + (size_t)(row0 + col) * 32 + quad * 8;
    f32x4 hv0 = *(const f32x4*)(hp), hv1 = *(const f32x4*)(hp + 4);
    s16x8 ahh, ahl;
#pragma unroll
    for (int i = 0; i < 4; ++i) {
        u16 h0 = f2bf(hv0[i]); ahh[i] = (short)h0;   ahl[i] = (short)f2bf(hv0[i] - bf2f(h0));
        u16 h1 = f2bf(hv1[i]); ahh[4+i] = (short)h1; ahl[4+i] = (short)f2bf(hv1[i] - bf2f(h1));
    }

    f32x4 gx[6], gh[6];
#pragma unroll
    for (int t = 0; t < 6; ++t) {
        s16x8 bh = *(const s16x8*)(wihh + t * 512 + lane * 8);
        s16x8 bl = *(const s16x8*)(wihl + t * 512 + lane * 8);
        f32x4 acc = {0,0,0,0};
        acc = __builtin_amdgcn_mfma_f32_16x16x32_bf16(anl, bh, acc, 0,0,0);
        acc = __builtin_amdgcn_mfma_f32_16x16x32_bf16(anh, bl, acc, 0,0,0);
        acc = __builtin_amdgcn_mfma_f32_16x16x32_bf16(anh, bh, acc, 0,0,0);
        gx[t] = acc;
        s16x8 ch = *(const s16x8*)(whhh + t * 512 + lane * 8);
        s16x8 cl = *(const s16x8*)(whhl + t * 512 + lane * 8);
        f32x4 acc2 = {0,0,0,0};
        acc2 = __builtin_amdgcn_mfma_f32_16x16x32_bf16(ahl, ch, acc2, 0,0,0);
        acc2 = __builtin_amdgcn_mfma_f32_16x16x32_bf16(ahh, cl, acc2, 0,0,0);
        acc2 = __builtin_amdgcn_mfma_f32_16x16x32_bf16(ahh, ch, acc2, 0,0,0);
        gh[t] = acc2;
    }
    float bihv[6], bhhv[6];
#pragma unroll
    for (int t = 0; t < 6; ++t) { bihv[t] = b_ih[t * 16 + col]; bhhv[t] = b_hh[t * 16 + col]; }

#pragma unroll
    for (int r = 0; r < 4; ++r) {
        int row = row0 + quad * 4 + r;
#pragma unroll
        for (int oh = 0; oh < 2; ++oh) {
            int o = oh * 16 + col;
            float hid = st_f32[(size_t)row * 32 + o];
            float sr = (gx[oh][r] + bihv[oh]) + (gh[oh][r] + bhhv[oh]);
            float sz = (gx[2+oh][r] + bihv[2+oh]) + (gh[2+oh][r] + bhhv[2+oh]);
            float gxn = gx[4+oh][r] + bihv[4+oh];
            float ghn = gh[4+oh][r] + bhhv[4+oh];
            float rr = 1.f / (1.f + __expf(-sr));
            float zz = 1.f / (1.f + __expf(-sz));
            float narg = gxn + rr * ghn;
            float ex = __expf(2.f * narg);
            float nn = (ex - 1.f) / (ex + 1.f);
            float hnew = (1.f - zz) * nn + zz * hid;
            out_f32[(size_t)row * 32 + o] = hnew;
        }
    }
}

// ---------------------------------------------------------------------------
extern "C" void kernel_launch(void* const* d_in, const int* in_sizes, int n_in,
                              void* d_out, int out_size, void* d_ws, size_t ws_size,
                              hipStream_t stream)
{
    const float* x      = (const float*)d_in[0];
    const float* er     = (const float*)d_in[1];
    const float* pw1    = (const float*)d_in[2];
    const float* pb1    = (const float*)d_in[3];
    const float* pw2    = (const float*)d_in[4];
    const float* pb2    = (const float*)d_in[5];
    const float* ew1    = (const float*)d_in[6];
    const float* eb1    = (const float*)d_in[7];
    const float* ew2    = (const float*)d_in[8];
    const float* eb2    = (const float*)d_in[9];
    const float* conv_b = (const float*)d_in[10];
    const float* wih    = (const float*)d_in[11];
    const float* whh    = (const float*)d_in[12];
    const float* bih    = (const float*)d_in[13];
    const float* bhh    = (const float*)d_in[14];
    const int*   esrc   = (const int*)d_in[15];
    const int*   edst   = (const int*)d_in[16];
    float* out = (float*)d_out;

    char* ws = (char*)d_ws;
    size_t off = 0;
    auto alloc = [&](size_t bytes) -> void* {
        void* p = ws + off;
        off = (off + bytes + 255) & ~(size_t)255;
        return p;
    };
    u16*   rbf    = (u16*)  alloc((size_t)(NEDGES + 32) * 32 * 2);
    float* st_f32 = (float*)alloc((size_t)ROWS * 32 * 4);
    float* agg    = (float*)alloc((size_t)ROWS * 32 * 4);
    u16*   ew2f   = (u16*)  alloc(64 * 512 * 2);
    u16*   pw1h   = (u16*)  alloc(2 * 512 * 2);
    u16*   pw1l   = (u16*)  alloc(2 * 512 * 2);
    u16*   pw2h   = (u16*)  alloc(2 * 512 * 2);
    u16*   pw2l   = (u16*)  alloc(2 * 512 * 2);
    u16*   wihhf  = (u16*)  alloc(6 * 512 * 2);
    u16*   wihlf  = (u16*)  alloc(6 * 512 * 2);
    u16*   whhhf  = (u16*)  alloc(6 * 512 * 2);
    u16*   whhlf  = (u16*)  alloc(6 * 512 * 2);
    // sort infrastructure
    int*   cnt      = (int*)alloc((size_t)NNODES * 4);
    int*   exc      = (int*)alloc((size_t)NNODES * 4);
    int*   bsum     = (int*)alloc(NBLK_SCAN * 4);
    int*   bofs     = (int*)alloc(NBLK_SCAN * 4);
    int*   esrcp    = (int*)alloc((size_t)(NEDGES + 32) * 4);
    int*   edstp    = (int*)alloc((size_t)(NEDGES + 32) * 4);
    (void)in_sizes; (void)n_in; (void)out_size; (void)ws_size;

    // --- one-time: sort edges by dst (hist fused with weight pack) ---
    hipMemsetAsync(cnt, 0, (size_t)NNODES * 4, stream);
    hist_pack_kernel<<<NEDGES / 256, 256, 0, stream>>>(
        edst, cnt, ew2, ew2f, pw1, pw1h, pw1l, pw2, pw2h, pw2l,
        wih, wihhf, wihlf, whh, whhhf, whhlf);
    scan1_kernel<<<NBLK_SCAN, 256, 0, stream>>>(cnt, exc, bsum);
    scan2_kernel<<<1, 256, 0, stream>>>(bsum, bofs);
    scatter_mlp_kernel<<<NEDGES / 256, 256, 0, stream>>>(
        edst, esrc, exc, bofs, cnt, esrcp, edstp, er, ew1, eb1, rbf);

    nodeproj_kernel<<<ROWS / 64, 256, 0, stream>>>(x, pw1h, pw1l, pb1, pw2h, pw2l, pb2,
                                                   st_f32, agg);
    for (int s = 0; s < 3; ++s) {
        msg_kernel<<<NEDGES / 64, 256, 0, stream>>>(rbf, ew2f, eb2, st_f32,
                                                    esrcp, edstp, agg);
        float* of = (s == 2) ? out : st_f32;
        gru_kernel<<<ROWS / 64, 256, 0, stream>>>(agg, conv_b, st_f32,
                                                  wihhf, wihlf, whhhf, whhlf, bih, bhh,
                                                  of, (s < 2) ? 1 : 0);
    }
}